// Round 8
// baseline (294.736 us; speedup 1.0000x reference)
//
#include <hip/hip_runtime.h>
#include <hip/hip_bf16.h>
#include <math.h>

#define N_EMBD 1024
#define N_HEAD 16
#define HEAD_DIM 64
#define BSZ 2
#define TSEQ 2048
#define C3 (3 * N_EMBD)

typedef __attribute__((ext_vector_type(8))) short short8_t;
typedef __attribute__((ext_vector_type(4))) float f32x4;
typedef __attribute__((address_space(3))) unsigned int lds_u32;
typedef const __attribute__((address_space(1))) unsigned int glb_u32;

__device__ __forceinline__ unsigned short f2bf(float f) {
  return __builtin_bit_cast(unsigned short, __float2bfloat16(f));
}

// ---------------- fp32 -> bf16 vectorized convert (8 elems/thread/iter) --------
__global__ __launch_bounds__(256) void conv_vec(
    const float* __restrict__ in, unsigned short* __restrict__ out, int n8)
{
  for (int i = blockIdx.x * blockDim.x + threadIdx.x; i < n8;
       i += gridDim.x * blockDim.x) {
    float4 a = ((const float4*)in)[2 * i];
    float4 b = ((const float4*)in)[2 * i + 1];
    union { unsigned short u[8]; uint4 q; } t;
    t.u[0] = f2bf(a.x); t.u[1] = f2bf(a.y); t.u[2] = f2bf(a.z); t.u[3] = f2bf(a.w);
    t.u[4] = f2bf(b.x); t.u[5] = f2bf(b.y); t.u[6] = f2bf(b.z); t.u[7] = f2bf(b.w);
    ((uint4*)out)[i] = t.q;
  }
}

// ------------- fp32 [K,N] -> bf16 [N,K] transpose-convert, 32x32 LDS tiles -----
__global__ __launch_bounds__(256) void conv_transpose(
    const float* __restrict__ in, unsigned short* __restrict__ out, int K, int N)
{
  __shared__ float tile[32][33];
  const int bk = blockIdx.y * 32, bn = blockIdx.x * 32;
  const int r = threadIdx.x >> 3, c4 = (threadIdx.x & 7) * 4;
  *(float4*)&tile[r][c4] = *(const float4*)(in + (size_t)(bk + r) * N + bn + c4);
  __syncthreads();
  union { unsigned short u[4]; uint2 q; } t;
#pragma unroll
  for (int j = 0; j < 4; ++j) t.u[j] = f2bf(tile[c4 + j][r]);
  *(uint2*)(out + (size_t)(bn + r) * K + bk + c4) = t.q;
}

// ---------------- bf16 MFMA GEMM: C[M,N] = A[M,K] @ Bt[N,K]^T + bias ----------
// 128x128 tile, BK=32, 256 thr = 4 waves (2x2), each wave 64x64 (4x4 frags).
// global_load_lds width-16, linear LDS dest, pre-swizzled source (rule #21);
// ds_read applies XOR (kq ^= row&3) -> 2-way bank aliasing (free, m136).
template <typename OUT_T>
__global__ __launch_bounds__(256) void gemm_mfma(
    const unsigned short* __restrict__ A,   // [M,K] bf16
    const unsigned short* __restrict__ Bt,  // [N,K] bf16
    const float* __restrict__ bias,         // [N]
    OUT_T* __restrict__ C, int M, int N, int K)
{
  constexpr int BM = 128, BN = 128, BK = 32;
  __shared__ __align__(16) unsigned short As[BM * BK];
  __shared__ __align__(16) unsigned short Bs[BN * BK];

  const int tid = threadIdx.x;
  const int l = tid & 63;
  const int g = l >> 4, c = l & 15;
  const int w = tid >> 6;
  const int wr = w >> 1, wc = w & 1;
  const int bm = blockIdx.y * BM, bn = blockIdx.x * BN;

  f32x4 acc[4][4];
#pragma unroll
  for (int i = 0; i < 4; i++)
#pragma unroll
    for (int j = 0; j < 4; j++) acc[i][j] = (f32x4){0.f, 0.f, 0.f, 0.f};

  // staging maps (2 issues per operand per K-step)
  int srow[2], skq[2];
#pragma unroll
  for (int i = 0; i < 2; i++) {
    int seg = i * 256 + tid;
    srow[i] = seg >> 2;
    skq[i] = (seg & 3) ^ (srow[i] & 3);
  }

  for (int k0 = 0; k0 < K; k0 += BK) {
    __syncthreads();
#pragma unroll
    for (int i = 0; i < 2; i++) {
      int seg = i * 256 + tid;
      __builtin_amdgcn_global_load_lds(
          (glb_u32*)(A + (size_t)(bm + srow[i]) * K + k0 + skq[i] * 8),
          (lds_u32*)((char*)As + seg * 16), 16, 0, 0);
      __builtin_amdgcn_global_load_lds(
          (glb_u32*)(Bt + (size_t)(bn + srow[i]) * K + k0 + skq[i] * 8),
          (lds_u32*)((char*)Bs + seg * 16), 16, 0, 0);
    }
    __syncthreads();

    short8_t af[4], bf[4];
#pragma unroll
    for (int mi = 0; mi < 4; mi++) {
      int row = wr * 64 + mi * 16 + c;
      af[mi] = *(const short8_t*)((char*)As + row * 64 + ((g * 16) ^ ((row & 3) << 4)));
    }
#pragma unroll
    for (int ni = 0; ni < 4; ni++) {
      int row = wc * 64 + ni * 16 + c;
      bf[ni] = *(const short8_t*)((char*)Bs + row * 64 + ((g * 16) ^ ((row & 3) << 4)));
    }
    __builtin_amdgcn_s_setprio(1);
#pragma unroll
    for (int mi = 0; mi < 4; mi++)
#pragma unroll
      for (int ni = 0; ni < 4; ni++)
        acc[mi][ni] = __builtin_amdgcn_mfma_f32_16x16x32_bf16(af[mi], bf[ni], acc[mi][ni], 0, 0, 0);
    __builtin_amdgcn_s_setprio(0);
  }

  float bv[4];
#pragma unroll
  for (int ni = 0; ni < 4; ni++) bv[ni] = bias[bn + wc * 64 + ni * 16 + c];
#pragma unroll
  for (int mi = 0; mi < 4; mi++)
#pragma unroll
    for (int j = 0; j < 4; j++) {
      int row = bm + wr * 64 + mi * 16 + g * 4 + j;
      OUT_T* cp = C + (size_t)row * N + bn + wc * 64 + c;
#pragma unroll
      for (int ni = 0; ni < 4; ni++) {
        float v = acc[mi][ni][j] + bv[ni];
        if constexpr (sizeof(OUT_T) == 2)
          *(unsigned short*)(cp + ni * 16) = f2bf(v);
        else
          *(float*)(cp + ni * 16) = v;
      }
    }
}

// ---------------- MFMA bf16 flash attention (bf16 qkv in, bf16 y out) ----------
// Round-7 changes: (1) reversed q-tile dispatch (heavy blocks first -> tail
// packing), (2) wave-uniform unmasked fast-path for fully-causal chunks,
// (3) log2-domain softmax (exp2, scale pre-folded) + exact wave-uniform
// defer-rescale (skip corr when no row's max moved -> bitwise identical).
__global__ __launch_bounds__(256) void attn_mfma(
    const unsigned short* __restrict__ qkv, unsigned short* __restrict__ y)
{
  const int l = threadIdx.x & 63;
  const int w = threadIdx.x >> 6;
  const int b = blockIdx.z, h = blockIdx.y;
  const int r0 = (gridDim.x - 1 - blockIdx.x) * 64;   // heavy tiles first
  const int g = l >> 4;
  const int c = l & 15;

  __shared__ __align__(16) unsigned short Ks[64 * 64];
  __shared__ __align__(16) unsigned short Vt[64 * 64];
  __shared__ __align__(16) unsigned short Ps[4][16 * 64];

  const unsigned short* base = qkv + (size_t)b * TSEQ * C3;
  const int qr0 = r0 + w * 16;
  const float SCALE_LOG2E = 0.125f * 1.44269504f;

  short8_t qf[2];
  {
    const unsigned short* qp = base + (size_t)(qr0 + c) * C3 + h * HEAD_DIM + g * 8;
    qf[0] = *(const short8_t*)(qp);
    qf[1] = *(const short8_t*)(qp + 32);
  }

  f32x4 o[4];
  float m[4], ld[4];
#pragma unroll
  for (int dt = 0; dt < 4; ++dt) o[dt] = (f32x4){0.f, 0.f, 0.f, 0.f};
#pragma unroll
  for (int r = 0; r < 4; ++r) { m[r] = -1e30f; ld[r] = 0.f; }

  const int nch = r0 / 64 + 1;
  for (int ci = 0; ci < nch; ++ci) {
    const int k0 = ci * 64;
    __syncthreads();
    // ---- stage K: 64x64 bf16 row-major, XOR-swizzled ----
#pragma unroll
    for (int s = 0; s < 2; ++s) {
      int seg = threadIdx.x + s * 256;
      int kr = seg >> 3, d8 = (seg & 7) * 8;
      uint4 t = *(const uint4*)(base + (size_t)(k0 + kr) * C3 + N_EMBD + h * HEAD_DIM + d8);
      *(uint4*)((char*)Ks + kr * 128 + ((d8 * 2) ^ ((kr & 7) << 4))) = t;
    }
    // ---- stage V transposed: Vt[d][k], swizzled ----
    {
      int dd = threadIdx.x & 63, kq = (threadIdx.x >> 6) * 16;
      const unsigned short* vp = base + (size_t)(k0 + kq) * C3 + 2 * N_EMBD + h * HEAD_DIM + dd;
      union { unsigned short u[16]; uint4 q[2]; } t;
#pragma unroll
      for (int j = 0; j < 16; ++j) t.u[j] = vp[(size_t)j * C3];
      char* vrow = (char*)Vt + dd * 128;
      *(uint4*)(vrow + ((kq * 2) ^ ((dd & 7) << 4)))      = t.q[0];
      *(uint4*)(vrow + ((kq * 2 + 16) ^ ((dd & 7) << 4))) = t.q[1];
    }
    __syncthreads();
    if (k0 > qr0 + 15) continue;

    // ---- S = Q K^T ----
    f32x4 st[4];
    __builtin_amdgcn_s_setprio(1);
#pragma unroll
    for (int kt = 0; kt < 4; ++kt) {
      const int row = kt * 16 + c;
      short8_t kf0 = *(const short8_t*)((const char*)Ks + row * 128 + ((g * 16) ^ ((row & 7) << 4)));
      short8_t kf1 = *(const short8_t*)((const char*)Ks + row * 128 + ((64 + g * 16) ^ ((row & 7) << 4)));
      f32x4 a2 = (f32x4){0.f, 0.f, 0.f, 0.f};
      a2 = __builtin_amdgcn_mfma_f32_16x16x32_bf16(qf[0], kf0, a2, 0, 0, 0);
      a2 = __builtin_amdgcn_mfma_f32_16x16x32_bf16(qf[1], kf1, a2, 0, 0, 0);
      st[kt] = a2;
    }
    __builtin_amdgcn_s_setprio(0);

    // ---- online softmax, log2 domain (C-layout: col=c key, row=g*4+r query) --
    const bool full = (k0 + 63 <= qr0);   // wave-uniform: no masking needed
    float mx[4];
#pragma unroll
    for (int r = 0; r < 4; ++r) {
      const int qg = qr0 + g * 4 + r;
      float v = -1e30f;
#pragma unroll
      for (int kt = 0; kt < 4; ++kt) {
        float s = st[kt][r] * SCALE_LOG2E;
        if (!full) { int kg = k0 + kt * 16 + c; if (kg > qg) s = -1e30f; }
        st[kt][r] = s;
        v = fmaxf(v, s);
      }
      v = fmaxf(v, __shfl_xor(v, 1));
      v = fmaxf(v, __shfl_xor(v, 2));
      v = fmaxf(v, __shfl_xor(v, 4));
      v = fmaxf(v, __shfl_xor(v, 8));
      mx[r] = v;
    }
    // exact defer-rescale: skip corr entirely when no row's max moved
    int need = (mx[0] > m[0]) | (mx[1] > m[1]) | (mx[2] > m[2]) | (mx[3] > m[3]);
    if (__any(need)) {
#pragma unroll
      for (int r = 0; r < 4; ++r) {
        float mnew = fmaxf(m[r], mx[r]);
        float corr = exp2f(m[r] - mnew);
        m[r] = mnew;
        ld[r] *= corr;
#pragma unroll
        for (int dt = 0; dt < 4; ++dt) o[dt][r] *= corr;
      }
    }
#pragma unroll
    for (int r = 0; r < 4; ++r) {
      float rs = 0.f;
      const int row = g * 4 + r;
#pragma unroll
      for (int kt = 0; kt < 4; ++kt) {
        float p = exp2f(st[kt][r] - m[r]);   // masked: 2^(-1e30-m) == 0
        rs += p;
        *(unsigned short*)((char*)Ps[w] + row * 128 +
                           (((kt * 16 + c) * 2) ^ ((row & 7) << 4))) = f2bf(p);
      }
      rs += __shfl_xor(rs, 1);
      rs += __shfl_xor(rs, 2);
      rs += __shfl_xor(rs, 4);
      rs += __shfl_xor(rs, 8);
      ld[r] += rs;
    }
    // ---- O += P V ----
    short8_t pf[2];
#pragma unroll
    for (int kc = 0; kc < 2; ++kc)
      pf[kc] = *(const short8_t*)((const char*)Ps[w] + c * 128 +
                                  ((64 * kc + g * 16) ^ ((c & 7) << 4)));
    __builtin_amdgcn_s_setprio(1);
#pragma unroll
    for (int dt = 0; dt < 4; ++dt) {
      const int row = dt * 16 + c;
#pragma unroll
      for (int kc = 0; kc < 2; ++kc) {
        short8_t vf = *(const short8_t*)((const char*)Vt + row * 128 +
                                         ((64 * kc + g * 16) ^ ((row & 7) << 4)));
        o[dt] = __builtin_amdgcn_mfma_f32_16x16x32_bf16(pf[kc], vf, o[dt], 0, 0, 0);
      }
    }
    __builtin_amdgcn_s_setprio(0);
  }
  // ---- epilogue: write bf16 ----
#pragma unroll
  for (int r = 0; r < 4; ++r) {
    float inv = 1.f / ld[r];
    const size_t rowoff = ((size_t)b * TSEQ + qr0 + g * 4 + r) * N_EMBD + h * HEAD_DIM;
#pragma unroll
    for (int dt = 0; dt < 4; ++dt)
      y[rowoff + dt * 16 + c] = f2bf(o[dt][r] * inv);
  }
}

extern "C" void kernel_launch(void* const* d_in, const int* in_sizes, int n_in,
                              void* d_out, int out_size, void* d_ws, size_t ws_size,
                              hipStream_t stream) {
  const float* x      = (const float*)d_in[0];
  const float* W_attn = (const float*)d_in[1];
  const float* b_attn = (const float*)d_in[2];
  const float* W_proj = (const float*)d_in[3];
  const float* b_proj = (const float*)d_in[4];
  float* out = (float*)d_out;

  const int M = BSZ * TSEQ;  // 4096

  unsigned short* xb   = (unsigned short*)d_ws;                 // [M,C]    8.4 MB
  unsigned short* Wta  = xb + (size_t)M * N_EMBD;               // [3C,C]   6.3 MB
  unsigned short* Wtp  = Wta + (size_t)C3 * N_EMBD;             // [C,C]    2.1 MB
  unsigned short* qkvb = Wtp + (size_t)N_EMBD * N_EMBD;         // [B,T,3C] 25.2 MB
  unsigned short* yatt = qkvb + (size_t)M * C3;                 // [B,T,C]  8.4 MB

  conv_vec<<<2048, 256, 0, stream>>>(x, xb, M * N_EMBD / 8);
  conv_transpose<<<dim3(C3 / 32, N_EMBD / 32), 256, 0, stream>>>(W_attn, Wta, N_EMBD, C3);
  conv_transpose<<<dim3(N_EMBD / 32, N_EMBD / 32), 256, 0, stream>>>(W_proj, Wtp, N_EMBD, N_EMBD);

  gemm_mfma<unsigned short><<<dim3(C3 / 128, M / 128), 256, 0, stream>>>(
      xb, Wta, b_attn, qkvb, M, C3, N_EMBD);

  attn_mfma<<<dim3(TSEQ / 64, N_HEAD, BSZ), 256, 0, stream>>>(qkvb, yatt);

  gemm_mfma<float><<<dim3(N_EMBD / 128, M / 128), 256, 0, stream>>>(
      yatt, Wtp, b_proj, out, M, N_EMBD, N_EMBD);
}

// Round 9
// 227.231 us; speedup vs baseline: 1.2971x; 1.2971x over previous
//
#include <hip/hip_runtime.h>
#include <hip/hip_bf16.h>
#include <math.h>

#define N_EMBD 1024
#define N_HEAD 16
#define HEAD_DIM 64
#define BSZ 2
#define TSEQ 2048
#define C3 (3 * N_EMBD)

typedef __attribute__((ext_vector_type(8))) short short8_t;
typedef __attribute__((ext_vector_type(4))) float f32x4;
typedef __attribute__((address_space(3))) unsigned int lds_u32;
typedef const __attribute__((address_space(1))) unsigned int glb_u32;

__device__ __forceinline__ unsigned short f2bf(float f) {
  return __builtin_bit_cast(unsigned short, __float2bfloat16(f));
}

// ---------------- fp32 -> bf16 vectorized convert (8 elems/thread/iter) --------
__global__ __launch_bounds__(256) void conv_vec(
    const float* __restrict__ in, unsigned short* __restrict__ out, int n8)
{
  for (int i = blockIdx.x * blockDim.x + threadIdx.x; i < n8;
       i += gridDim.x * blockDim.x) {
    float4 a = ((const float4*)in)[2 * i];
    float4 b = ((const float4*)in)[2 * i + 1];
    union { unsigned short u[8]; uint4 q; } t;
    t.u[0] = f2bf(a.x); t.u[1] = f2bf(a.y); t.u[2] = f2bf(a.z); t.u[3] = f2bf(a.w);
    t.u[4] = f2bf(b.x); t.u[5] = f2bf(b.y); t.u[6] = f2bf(b.z); t.u[7] = f2bf(b.w);
    ((uint4*)out)[i] = t.q;
  }
}

// ------------- fp32 [K,N] -> bf16 [N,K] transpose-convert, 32x32 LDS tiles -----
__global__ __launch_bounds__(256) void conv_transpose(
    const float* __restrict__ in, unsigned short* __restrict__ out, int K, int N)
{
  __shared__ float tile[32][33];
  const int bk = blockIdx.y * 32, bn = blockIdx.x * 32;
  const int r = threadIdx.x >> 3, c4 = (threadIdx.x & 7) * 4;
  *(float4*)&tile[r][c4] = *(const float4*)(in + (size_t)(bk + r) * N + bn + c4);
  __syncthreads();
  union { unsigned short u[4]; uint2 q; } t;
#pragma unroll
  for (int j = 0; j < 4; ++j) t.u[j] = f2bf(tile[c4 + j][r]);
  *(uint2*)(out + (size_t)(bn + r) * K + bk + c4) = t.q;
}

// ---------------- bf16 MFMA GEMM: C[M,N] = A[M,K] @ Bt[N,K]^T + bias ----------
// 128x128 tile, BK=32, 256 thr = 4 waves (2x2), each wave 64x64 (4x4 frags).
template <typename OUT_T>
__global__ __launch_bounds__(256) void gemm_mfma(
    const unsigned short* __restrict__ A,   // [M,K] bf16
    const unsigned short* __restrict__ Bt,  // [N,K] bf16
    const float* __restrict__ bias,         // [N]
    OUT_T* __restrict__ C, int M, int N, int K)
{
  constexpr int BM = 128, BN = 128, BK = 32;
  __shared__ __align__(16) unsigned short As[BM * BK];
  __shared__ __align__(16) unsigned short Bs[BN * BK];

  const int tid = threadIdx.x;
  const int l = tid & 63;
  const int g = l >> 4, c = l & 15;
  const int w = tid >> 6;
  const int wr = w >> 1, wc = w & 1;
  const int bm = blockIdx.y * BM, bn = blockIdx.x * BN;

  f32x4 acc[4][4];
#pragma unroll
  for (int i = 0; i < 4; i++)
#pragma unroll
    for (int j = 0; j < 4; j++) acc[i][j] = (f32x4){0.f, 0.f, 0.f, 0.f};

  // staging maps (2 issues per operand per K-step)
  int srow[2], skq[2];
#pragma unroll
  for (int i = 0; i < 2; i++) {
    int seg = i * 256 + tid;
    srow[i] = seg >> 2;
    skq[i] = (seg & 3) ^ (srow[i] & 3);
  }

  for (int k0 = 0; k0 < K; k0 += BK) {
    __syncthreads();
#pragma unroll
    for (int i = 0; i < 2; i++) {
      int seg = i * 256 + tid;
      __builtin_amdgcn_global_load_lds(
          (glb_u32*)(A + (size_t)(bm + srow[i]) * K + k0 + skq[i] * 8),
          (lds_u32*)((char*)As + seg * 16), 16, 0, 0);
      __builtin_amdgcn_global_load_lds(
          (glb_u32*)(Bt + (size_t)(bn + srow[i]) * K + k0 + skq[i] * 8),
          (lds_u32*)((char*)Bs + seg * 16), 16, 0, 0);
    }
    __syncthreads();

    short8_t af[4], bf[4];
#pragma unroll
    for (int mi = 0; mi < 4; mi++) {
      int row = wr * 64 + mi * 16 + c;
      af[mi] = *(const short8_t*)((char*)As + row * 64 + ((g * 16) ^ ((row & 3) << 4)));
    }
#pragma unroll
    for (int ni = 0; ni < 4; ni++) {
      int row = wc * 64 + ni * 16 + c;
      bf[ni] = *(const short8_t*)((char*)Bs + row * 64 + ((g * 16) ^ ((row & 3) << 4)));
    }
    __builtin_amdgcn_s_setprio(1);
#pragma unroll
    for (int mi = 0; mi < 4; mi++)
#pragma unroll
      for (int ni = 0; ni < 4; ni++)
        acc[mi][ni] = __builtin_amdgcn_mfma_f32_16x16x32_bf16(af[mi], bf[ni], acc[mi][ni], 0, 0, 0);
    __builtin_amdgcn_s_setprio(0);
  }

  float bv[4];
#pragma unroll
  for (int ni = 0; ni < 4; ni++) bv[ni] = bias[bn + wc * 64 + ni * 16 + c];
#pragma unroll
  for (int mi = 0; mi < 4; mi++)
#pragma unroll
    for (int j = 0; j < 4; j++) {
      int row = bm + wr * 64 + mi * 16 + g * 4 + j;
      OUT_T* cp = C + (size_t)row * N + bn + wc * 64 + c;
#pragma unroll
      for (int ni = 0; ni < 4; ni++) {
        float v = acc[mi][ni][j] + bv[ni];
        if constexpr (sizeof(OUT_T) == 2)
          *(unsigned short*)(cp + ni * 16) = f2bf(v);
        else
          *(float*)(cp + ni * 16) = v;
      }
    }
}

// ---------------- MFMA bf16 flash attention (bf16 qkv in, bf16 y out) ----------
// Round-9 change: uniform work pairing. Each block processes TWO q-tiles,
// tile (31-pair) then tile (pair): (32-pair)+(pair+1) = 33 chunks for every
// block -> no triangular retirement tail, 8 waves/CU for the whole kernel.
// Inner body identical to the verified 151.7us round-7 structure.
__global__ __launch_bounds__(256) void attn_mfma(
    const unsigned short* __restrict__ qkv, unsigned short* __restrict__ y)
{
  const int l = threadIdx.x & 63;
  const int w = threadIdx.x >> 6;
  const int b = blockIdx.z, h = blockIdx.y;
  const int pair = blockIdx.x;          // 0..15
  const int g = l >> 4;
  const int c = l & 15;

  __shared__ __align__(16) unsigned short Ks[64 * 64];
  __shared__ __align__(16) unsigned short Vt[64 * 64];
  __shared__ __align__(16) unsigned short Ps[4][16 * 64];

  const unsigned short* base = qkv + (size_t)b * TSEQ * C3;

#pragma unroll 1
  for (int half = 0; half < 2; ++half) {
    const int tile = half == 0 ? (31 - pair) : pair;   // heavy tile first
    const int r0 = tile * 64;
    const int qr0 = r0 + w * 16;

    short8_t qf[2];
    {
      const unsigned short* qp = base + (size_t)(qr0 + c) * C3 + h * HEAD_DIM + g * 8;
      qf[0] = *(const short8_t*)(qp);
      qf[1] = *(const short8_t*)(qp + 32);
    }

    f32x4 o[4];
    float m[4], ld[4];
#pragma unroll
    for (int dt = 0; dt < 4; ++dt) o[dt] = (f32x4){0.f, 0.f, 0.f, 0.f};
#pragma unroll
    for (int r = 0; r < 4; ++r) { m[r] = -1e30f; ld[r] = 0.f; }

    const int nch = tile + 1;
#pragma unroll 1
    for (int ci = 0; ci < nch; ++ci) {
      const int k0 = ci * 64;
      __syncthreads();
      // ---- stage K: 64x64 bf16 row-major, XOR-swizzled ----
#pragma unroll
      for (int s = 0; s < 2; ++s) {
        int seg = threadIdx.x + s * 256;
        int kr = seg >> 3, d8 = (seg & 7) * 8;
        uint4 t = *(const uint4*)(base + (size_t)(k0 + kr) * C3 + N_EMBD + h * HEAD_DIM + d8);
        *(uint4*)((char*)Ks + kr * 128 + ((d8 * 2) ^ ((kr & 7) << 4))) = t;
      }
      // ---- stage V transposed: Vt[d][k], swizzled ----
      {
        int dd = threadIdx.x & 63, kq = (threadIdx.x >> 6) * 16;
        const unsigned short* vp = base + (size_t)(k0 + kq) * C3 + 2 * N_EMBD + h * HEAD_DIM + dd;
        union { unsigned short u[16]; uint4 q[2]; } t;
#pragma unroll
        for (int j = 0; j < 16; ++j) t.u[j] = vp[(size_t)j * C3];
        char* vrow = (char*)Vt + dd * 128;
        *(uint4*)(vrow + ((kq * 2) ^ ((dd & 7) << 4)))      = t.q[0];
        *(uint4*)(vrow + ((kq * 2 + 16) ^ ((dd & 7) << 4))) = t.q[1];
      }
      __syncthreads();
      if (k0 > qr0 + 15) continue;

      // ---- S = Q K^T ----
      f32x4 st[4];
      __builtin_amdgcn_s_setprio(1);
#pragma unroll
      for (int kt = 0; kt < 4; ++kt) {
        const int row = kt * 16 + c;
        short8_t kf0 = *(const short8_t*)((const char*)Ks + row * 128 + ((g * 16) ^ ((row & 7) << 4)));
        short8_t kf1 = *(const short8_t*)((const char*)Ks + row * 128 + ((64 + g * 16) ^ ((row & 7) << 4)));
        f32x4 a2 = (f32x4){0.f, 0.f, 0.f, 0.f};
        a2 = __builtin_amdgcn_mfma_f32_16x16x32_bf16(qf[0], kf0, a2, 0, 0, 0);
        a2 = __builtin_amdgcn_mfma_f32_16x16x32_bf16(qf[1], kf1, a2, 0, 0, 0);
        st[kt] = a2;
      }
      __builtin_amdgcn_s_setprio(0);
      // ---- online softmax (C-layout: col=c key, row=g*4+r query) ----
#pragma unroll
      for (int r = 0; r < 4; ++r) {
        const int qg = qr0 + g * 4 + r;
        float mx = -1e30f;
#pragma unroll
        for (int kt = 0; kt < 4; ++kt) {
          int kg = k0 + kt * 16 + c;
          float s = (kg <= qg) ? st[kt][r] * 0.125f : -1e30f;
          st[kt][r] = s;
          mx = fmaxf(mx, s);
        }
        mx = fmaxf(mx, __shfl_xor(mx, 1));
        mx = fmaxf(mx, __shfl_xor(mx, 2));
        mx = fmaxf(mx, __shfl_xor(mx, 4));
        mx = fmaxf(mx, __shfl_xor(mx, 8));
        float mnew = fmaxf(m[r], mx);
        float corr = __expf(m[r] - mnew);
        m[r] = mnew;
        float rs = 0.f;
        const int row = g * 4 + r;
#pragma unroll
        for (int kt = 0; kt < 4; ++kt) {
          int kg = k0 + kt * 16 + c;
          float p = (kg <= qg) ? __expf(st[kt][r] - mnew) : 0.f;
          rs += p;
          *(unsigned short*)((char*)Ps[w] + row * 128 +
                             (((kt * 16 + c) * 2) ^ ((row & 7) << 4))) = f2bf(p);
        }
        rs += __shfl_xor(rs, 1);
        rs += __shfl_xor(rs, 2);
        rs += __shfl_xor(rs, 4);
        rs += __shfl_xor(rs, 8);
        ld[r] = ld[r] * corr + rs;
#pragma unroll
        for (int dt = 0; dt < 4; ++dt) o[dt][r] *= corr;
      }
      // ---- O += P V ----
      short8_t pf[2];
#pragma unroll
      for (int kc = 0; kc < 2; ++kc)
        pf[kc] = *(const short8_t*)((const char*)Ps[w] + c * 128 +
                                    ((64 * kc + g * 16) ^ ((c & 7) << 4)));
      __builtin_amdgcn_s_setprio(1);
#pragma unroll
      for (int dt = 0; dt < 4; ++dt) {
        const int row = dt * 16 + c;
#pragma unroll
        for (int kc = 0; kc < 2; ++kc) {
          short8_t vf = *(const short8_t*)((const char*)Vt + row * 128 +
                                           ((64 * kc + g * 16) ^ ((row & 7) << 4)));
          o[dt] = __builtin_amdgcn_mfma_f32_16x16x32_bf16(pf[kc], vf, o[dt], 0, 0, 0);
        }
      }
      __builtin_amdgcn_s_setprio(0);
    }
    // ---- epilogue: write bf16 ----
#pragma unroll
    for (int r = 0; r < 4; ++r) {
      float inv = 1.f / ld[r];
      const size_t rowoff = ((size_t)b * TSEQ + qr0 + g * 4 + r) * N_EMBD + h * HEAD_DIM;
#pragma unroll
      for (int dt = 0; dt < 4; ++dt)
        y[rowoff + dt * 16 + c] = f2bf(o[dt][r] * inv);
    }
  }
}

extern "C" void kernel_launch(void* const* d_in, const int* in_sizes, int n_in,
                              void* d_out, int out_size, void* d_ws, size_t ws_size,
                              hipStream_t stream) {
  const float* x      = (const float*)d_in[0];
  const float* W_attn = (const float*)d_in[1];
  const float* b_attn = (const float*)d_in[2];
  const float* W_proj = (const float*)d_in[3];
  const float* b_proj = (const float*)d_in[4];
  float* out = (float*)d_out;

  const int M = BSZ * TSEQ;  // 4096

  unsigned short* xb   = (unsigned short*)d_ws;                 // [M,C]    8.4 MB
  unsigned short* Wta  = xb + (size_t)M * N_EMBD;               // [3C,C]   6.3 MB
  unsigned short* Wtp  = Wta + (size_t)C3 * N_EMBD;             // [C,C]    2.1 MB
  unsigned short* qkvb = Wtp + (size_t)N_EMBD * N_EMBD;         // [B,T,3C] 25.2 MB
  unsigned short* yatt = qkvb + (size_t)M * C3;                 // [B,T,C]  8.4 MB

  conv_vec<<<2048, 256, 0, stream>>>(x, xb, M * N_EMBD / 8);
  conv_transpose<<<dim3(C3 / 32, N_EMBD / 32), 256, 0, stream>>>(W_attn, Wta, N_EMBD, C3);
  conv_transpose<<<dim3(N_EMBD / 32, N_EMBD / 32), 256, 0, stream>>>(W_proj, Wtp, N_EMBD, N_EMBD);

  gemm_mfma<unsigned short><<<dim3(C3 / 128, M / 128), 256, 0, stream>>>(
      xb, Wta, b_attn, qkvb, M, C3, N_EMBD);

  // paired q-tiles: grid.x = (T/64)/2 = 16, each block does 2 tiles (33 chunks)
  attn_mfma<<<dim3(TSEQ / 128, N_HEAD, BSZ), 256, 0, stream>>>(qkvb, yatt);

  gemm_mfma<float><<<dim3(N_EMBD / 128, M / 128), 256, 0, stream>>>(
      yatt, Wtp, b_proj, out, M, N_EMBD, N_EMBD);
}